// Round 1
// baseline (607.444 us; speedup 1.0000x reference)
//
#include <hip/hip_runtime.h>

typedef unsigned short ushort;
typedef unsigned int uint;
typedef __bf16 bf16x8 __attribute__((ext_vector_type(8)));
typedef unsigned short u16x8 __attribute__((ext_vector_type(8)));
typedef float f32x4 __attribute__((ext_vector_type(4)));

__device__ __forceinline__ ushort f2bf(float f) {
  uint u = __builtin_bit_cast(uint, f);
  u += 0x7fffu + ((u >> 16) & 1u);
  return (ushort)(u >> 16);
}

__device__ __forceinline__ f32x4 mfma_bf16(u16x8 a, u16x8 b, f32x4 c) {
  return __builtin_amdgcn_mfma_f32_16x16x32_bf16(
      __builtin_bit_cast(bf16x8, a), __builtin_bit_cast(bf16x8, b), c, 0, 0, 0);
}

// W[k][N] fp32 -> WT[n][512] bf16   (K fixed at 512)
__global__ void cvt_transpose(const float* __restrict__ W, ushort* __restrict__ WT,
                              int N, int total) {
  int idx = blockIdx.x * 256 + threadIdx.x;
  if (idx >= total) return;
  int n = idx >> 9, k = idx & 511;
  WT[idx] = f2bf(W[(size_t)k * N + n]);
}

// C[M,1536] bf16 = X[M,512] fp32 @ BT[1536,512]^T ; 128x128 tile, BK=32, 4 waves
__global__ __launch_bounds__(256) void gemm_qkv(const float* __restrict__ X,
                                                const ushort* __restrict__ BT,
                                                ushort* __restrict__ C) {
  __shared__ __align__(16) ushort as_[128 * 32];
  __shared__ __align__(16) ushort bs_[128 * 32];
  const int tid = threadIdx.x;
  const int lane = tid & 63;
  const int wid = tid >> 6;
  const int c16 = lane & 15, q4 = lane >> 4;
  const int m0 = blockIdx.x * 128;
  const int n0 = blockIdx.y * 128;
  const int wr = (wid >> 1) * 64, wc = (wid & 1) * 64;

  f32x4 acc[4][4];
#pragma unroll
  for (int m = 0; m < 4; ++m)
#pragma unroll
    for (int n = 0; n < 4; ++n) acc[m][n] = f32x4{0.f, 0.f, 0.f, 0.f};

  const float* aptr = X + (size_t)(m0 + (tid >> 1)) * 512 + (tid & 1) * 16;
  const ushort* bptr = BT + (size_t)(n0 + (tid >> 2)) * 512 + (tid & 3) * 8;
  ushort* awr = as_ + (tid >> 1) * 32 + (tid & 1) * 16;
  auto bl0 = (__attribute__((address_space(3))) uint*)(bs_ + tid * 8);
  auto bl1 = (__attribute__((address_space(3))) uint*)(bs_ + 2048 + tid * 8);

  const ushort* ard = as_ + (wr + c16) * 32 + q4 * 8;
  const ushort* brd = bs_ + (wc + c16) * 32 + q4 * 8;

  for (int k0 = 0; k0 < 512; k0 += 32) {
    if (k0) __syncthreads();
    __builtin_amdgcn_global_load_lds(
        (__attribute__((address_space(1))) uint*)(bptr + k0), bl0, 16, 0, 0);
    __builtin_amdgcn_global_load_lds(
        (__attribute__((address_space(1))) uint*)(bptr + 64 * 512 + k0), bl1, 16, 0, 0);
    f32x4 a0 = *(const f32x4*)(aptr + k0);
    f32x4 a1 = *(const f32x4*)(aptr + k0 + 4);
    f32x4 a2 = *(const f32x4*)(aptr + k0 + 8);
    f32x4 a3 = *(const f32x4*)(aptr + k0 + 12);
    u16x8 p0, p1;
#pragma unroll
    for (int j = 0; j < 4; ++j) {
      p0[j] = f2bf(a0[j]); p0[j + 4] = f2bf(a1[j]);
      p1[j] = f2bf(a2[j]); p1[j + 4] = f2bf(a3[j]);
    }
    *reinterpret_cast<u16x8*>(awr) = p0;
    *reinterpret_cast<u16x8*>(awr + 8) = p1;
    __syncthreads();
    u16x8 af[4], bf[4];
#pragma unroll
    for (int m = 0; m < 4; ++m) af[m] = *reinterpret_cast<const u16x8*>(ard + m * 512);
#pragma unroll
    for (int n = 0; n < 4; ++n) bf[n] = *reinterpret_cast<const u16x8*>(brd + n * 512);
#pragma unroll
    for (int m = 0; m < 4; ++m)
#pragma unroll
      for (int n = 0; n < 4; ++n) acc[m][n] = mfma_bf16(af[m], bf[n], acc[m][n]);
  }
  const int row0 = m0 + wr + q4 * 4;
  const int col0 = n0 + wc + c16;
#pragma unroll
  for (int m = 0; m < 4; ++m)
#pragma unroll
    for (int r = 0; r < 4; ++r) {
      ushort* cp = C + (size_t)(row0 + m * 16 + r) * 1536 + col0;
      cp[0]  = f2bf(acc[m][0][r]);
      cp[16] = f2bf(acc[m][1][r]);
      cp[32] = f2bf(acc[m][2][r]);
      cp[48] = f2bf(acc[m][3][r]);
    }
}

// per-window attention: one wave per (b, g, head)
__global__ __launch_bounds__(256) void attn_win(const ushort* __restrict__ qkv,
                                                ushort* __restrict__ O) {
  __shared__ __align__(16) ushort p_lds[4][4096];
  __shared__ __align__(16) ushort v_lds[4][4096];
  const int tid = threadIdx.x, lane = tid & 63, w = tid >> 6;
  const int wg = blockIdx.x * 4 + w;
  const int head = wg & 7, g = (wg >> 3) & 63, b = wg >> 9;
  const int gh = g >> 3, gw = g & 7;
  const int c16 = lane & 15, q4 = lane >> 4;
  const size_t brow = (size_t)b * 3136;
  const u16x8 Z = {0, 0, 0, 0, 0, 0, 0, 0};

  int rowq[4]; bool val[4];
#pragma unroll
  for (int i = 0; i < 4; ++i) {
    int s = i * 16 + c16;
    val[i] = (s < 49);
    int ss = val[i] ? s : 0;
    rowq[i] = (gh * 7 + ss / 7) * 56 + gw * 7 + ss % 7;
  }
  const int qc = head * 64 + q4 * 8;

  u16x8 qf[2][4], kf[2][4];
#pragma unroll
  for (int i = 0; i < 4; ++i) {
    const ushort* p = qkv + (brow + rowq[i]) * 1536 + qc;
#pragma unroll
    for (int kk = 0; kk < 2; ++kk) {
      qf[kk][i] = val[i] ? *reinterpret_cast<const u16x8*>(p + kk * 32) : Z;
      kf[kk][i] = val[i] ? *reinterpret_cast<const u16x8*>(p + 512 + kk * 32) : Z;
    }
  }

  // stage V^T (XOR-swizzled): lane covers token t = lane
  {
    int t = lane < 49 ? lane : 0;
    const ushort* vp =
        qkv + (brow + ((gh * 7 + t / 7) * 56 + gw * 7 + t % 7)) * 1536 + 1024 + head * 64;
    u16x8 vr[8];
#pragma unroll
    for (int j = 0; j < 8; ++j)
      vr[j] = (lane < 49) ? *reinterpret_cast<const u16x8*>(vp + j * 8) : Z;
#pragma unroll
    for (int d = 0; d < 64; ++d)
      v_lds[w][(d * 64 + lane) ^ ((d & 7) << 3)] = vr[d >> 3][d & 7];
  }

  f32x4 acc[4][4];
#pragma unroll
  for (int m = 0; m < 4; ++m)
#pragma unroll
    for (int n = 0; n < 4; ++n) acc[m][n] = f32x4{0.f, 0.f, 0.f, 0.f};
#pragma unroll
  for (int kk = 0; kk < 2; ++kk)
#pragma unroll
    for (int m = 0; m < 4; ++m)
#pragma unroll
      for (int n = 0; n < 4; ++n)
        acc[m][n] = mfma_bf16(qf[kk][m], kf[kk][n], acc[m][n]);

  // softmax rows (cols n=0..2 always valid; n=3 valid only for c16==0) + P -> LDS
#pragma unroll
  for (int m = 0; m < 4; ++m)
#pragma unroll
    for (int r = 0; r < 4; ++r) {
      float s0 = acc[m][0][r] * 0.125f;
      float s1 = acc[m][1][r] * 0.125f;
      float s2 = acc[m][2][r] * 0.125f;
      float s3 = (c16 == 0) ? acc[m][3][r] * 0.125f : -1e30f;
      float mx = fmaxf(fmaxf(s0, s1), fmaxf(s2, s3));
#pragma unroll
      for (int off = 1; off < 16; off <<= 1) mx = fmaxf(mx, __shfl_xor(mx, off));
      s0 = __expf(s0 - mx);
      s1 = __expf(s1 - mx);
      s2 = __expf(s2 - mx);
      s3 = (c16 == 0) ? __expf(s3 - mx) : 0.f;
      float sum = s0 + s1 + s2 + s3;
#pragma unroll
      for (int off = 1; off < 16; off <<= 1) sum += __shfl_xor(sum, off);
      float inv = 1.f / sum;
      int row = m * 16 + q4 * 4 + r;
      int rb = row * 64, sw = (row & 7) << 3;
      p_lds[w][(rb + c16) ^ sw]      = f2bf(s0 * inv);
      p_lds[w][(rb + 16 + c16) ^ sw] = f2bf(s1 * inv);
      p_lds[w][(rb + 32 + c16) ^ sw] = f2bf(s2 * inv);
      p_lds[w][(rb + 48 + c16) ^ sw] = f2bf(s3 * inv);
    }
  __syncthreads();

  f32x4 o[4][4];
#pragma unroll
  for (int m = 0; m < 4; ++m)
#pragma unroll
    for (int n = 0; n < 4; ++n) o[m][n] = f32x4{0.f, 0.f, 0.f, 0.f};
#pragma unroll
  for (int kk = 0; kk < 2; ++kk) {
    u16x8 pa[4], vb[4];
#pragma unroll
    for (int m = 0; m < 4; ++m) {
      int row = m * 16 + c16;
      pa[m] = *reinterpret_cast<const u16x8*>(
          &p_lds[w][(row * 64 + kk * 32 + q4 * 8) ^ ((row & 7) << 3)]);
    }
#pragma unroll
    for (int n = 0; n < 4; ++n) {
      int d = n * 16 + c16;
      vb[n] = *reinterpret_cast<const u16x8*>(
          &v_lds[w][(d * 64 + kk * 32 + q4 * 8) ^ ((d & 7) << 3)]);
    }
#pragma unroll
    for (int m = 0; m < 4; ++m)
#pragma unroll
      for (int n = 0; n < 4; ++n) o[m][n] = mfma_bf16(pa[m], vb[n], o[m][n]);
  }

#pragma unroll
  for (int m = 0; m < 4; ++m)
#pragma unroll
    for (int r = 0; r < 4; ++r) {
      int s = m * 16 + q4 * 4 + r;
      if (s < 49) {
        int n_tok = (gh * 7 + s / 7) * 56 + gw * 7 + s % 7;
        ushort* op = O + (brow + n_tok) * 512 + head * 64 + c16;
        op[0]  = f2bf(o[m][0][r]);
        op[16] = f2bf(o[m][1][r]);
        op[32] = f2bf(o[m][2][r]);
        op[48] = f2bf(o[m][3][r]);
      }
    }
}

// C[M,512] fp32 = A[M,512] bf16 @ BT[512,512]^T + bias
__global__ __launch_bounds__(256) void gemm_proj(const ushort* __restrict__ A,
                                                 const ushort* __restrict__ BT,
                                                 const float* __restrict__ bias,
                                                 float* __restrict__ C) {
  __shared__ __align__(16) ushort as_[128 * 32];
  __shared__ __align__(16) ushort bs_[128 * 32];
  const int tid = threadIdx.x;
  const int lane = tid & 63;
  const int wid = tid >> 6;
  const int c16 = lane & 15, q4 = lane >> 4;
  const int m0 = blockIdx.x * 128, n0 = blockIdx.y * 128;
  const int wr = (wid >> 1) * 64, wc = (wid & 1) * 64;

  f32x4 acc[4][4];
#pragma unroll
  for (int m = 0; m < 4; ++m)
#pragma unroll
    for (int n = 0; n < 4; ++n) acc[m][n] = f32x4{0.f, 0.f, 0.f, 0.f};

  const ushort* aptr = A + (size_t)(m0 + (tid >> 2)) * 512 + (tid & 3) * 8;
  const ushort* bptr = BT + (size_t)(n0 + (tid >> 2)) * 512 + (tid & 3) * 8;
  auto al0 = (__attribute__((address_space(3))) uint*)(as_ + tid * 8);
  auto al1 = (__attribute__((address_space(3))) uint*)(as_ + 2048 + tid * 8);
  auto bl0 = (__attribute__((address_space(3))) uint*)(bs_ + tid * 8);
  auto bl1 = (__attribute__((address_space(3))) uint*)(bs_ + 2048 + tid * 8);
  const ushort* ard = as_ + (wr + c16) * 32 + q4 * 8;
  const ushort* brd = bs_ + (wc + c16) * 32 + q4 * 8;

  for (int k0 = 0; k0 < 512; k0 += 32) {
    if (k0) __syncthreads();
    __builtin_amdgcn_global_load_lds(
        (__attribute__((address_space(1))) uint*)(aptr + k0), al0, 16, 0, 0);
    __builtin_amdgcn_global_load_lds(
        (__attribute__((address_space(1))) uint*)(aptr + 64 * 512 + k0), al1, 16, 0, 0);
    __builtin_amdgcn_global_load_lds(
        (__attribute__((address_space(1))) uint*)(bptr + k0), bl0, 16, 0, 0);
    __builtin_amdgcn_global_load_lds(
        (__attribute__((address_space(1))) uint*)(bptr + 64 * 512 + k0), bl1, 16, 0, 0);
    __syncthreads();
    u16x8 af[4], bf[4];
#pragma unroll
    for (int m = 0; m < 4; ++m) af[m] = *reinterpret_cast<const u16x8*>(ard + m * 512);
#pragma unroll
    for (int n = 0; n < 4; ++n) bf[n] = *reinterpret_cast<const u16x8*>(brd + n * 512);
#pragma unroll
    for (int m = 0; m < 4; ++m)
#pragma unroll
      for (int n = 0; n < 4; ++n) acc[m][n] = mfma_bf16(af[m], bf[n], acc[m][n]);
  }
  const int row0 = m0 + wr + q4 * 4;
  const int col0 = n0 + wc + c16;
  const float b0 = bias[col0], b1 = bias[col0 + 16], b2 = bias[col0 + 32], b3 = bias[col0 + 48];
#pragma unroll
  for (int m = 0; m < 4; ++m)
#pragma unroll
    for (int r = 0; r < 4; ++r) {
      float* cp = C + (size_t)(row0 + m * 16 + r) * 512 + col0;
      cp[0]  = acc[m][0][r] + b0;
      cp[16] = acc[m][1][r] + b1;
      cp[32] = acc[m][2][r] + b2;
      cp[48] = acc[m][3][r] + b3;
    }
}

extern "C" void kernel_launch(void* const* d_in, const int* in_sizes, int n_in,
                              void* d_out, int out_size, void* d_ws, size_t ws_size,
                              hipStream_t stream) {
  const float* x      = (const float*)d_in[0];
  const float* w_qkv  = (const float*)d_in[1];
  const float* w_proj = (const float*)d_in[2];
  const float* b_proj = (const float*)d_in[3];
  char* ws = (char*)d_ws;
  ushort* wqkvT  = (ushort*)ws;                       // 1536*512*2  = 1,572,864 B
  ushort* wprojT = (ushort*)(ws + 1572864);           // 512*512*2   =   524,288 B
  ushort* qkv    = (ushort*)(ws + 2097152);           // 100352*1536*2 = 308,281,344 B
  ushort* attn   = (ushort*)(ws + 310378496);         // 100352*512*2  = 102,760,448 B
  float* out = (float*)d_out;

  cvt_transpose<<<3072, 256, 0, stream>>>(w_qkv, wqkvT, 1536, 1536 * 512);
  cvt_transpose<<<1024, 256, 0, stream>>>(w_proj, wprojT, 512, 512 * 512);
  gemm_qkv<<<dim3(784, 12), 256, 0, stream>>>(x, wqkvT, qkv);
  attn_win<<<4096, 256, 0, stream>>>(qkv, attn);
  gemm_proj<<<dim3(784, 4), 256, 0, stream>>>(attn, wprojT, b_proj, out);
}

// Round 2
// 520.685 us; speedup vs baseline: 1.1666x; 1.1666x over previous
//
#include <hip/hip_runtime.h>

typedef unsigned short ushort;
typedef unsigned int uint;
typedef __bf16 bf16x8 __attribute__((ext_vector_type(8)));
typedef unsigned short u16x8 __attribute__((ext_vector_type(8)));
typedef float f32x4 __attribute__((ext_vector_type(4)));

__device__ __forceinline__ ushort f2bf(float f) {
  uint u = __builtin_bit_cast(uint, f);
  u += 0x7fffu + ((u >> 16) & 1u);
  return (ushort)(u >> 16);
}

__device__ __forceinline__ f32x4 mfma_bf16(u16x8 a, u16x8 b, f32x4 c) {
  return __builtin_amdgcn_mfma_f32_16x16x32_bf16(
      __builtin_bit_cast(bf16x8, a), __builtin_bit_cast(bf16x8, b), c, 0, 0, 0);
}

// x fp32 -> bf16, vectorized 8/thread, grid-stride
__global__ __launch_bounds__(256) void cvt_x(const float* __restrict__ X,
                                             ushort* __restrict__ Xb, int total8) {
  int stride = gridDim.x * 256;
  for (int i = blockIdx.x * 256 + threadIdx.x; i < total8; i += stride) {
    f32x4 a = ((const f32x4*)X)[2 * i];
    f32x4 b = ((const f32x4*)X)[2 * i + 1];
    u16x8 o;
#pragma unroll
    for (int j = 0; j < 4; ++j) { o[j] = f2bf(a[j]); o[j + 4] = f2bf(b[j]); }
    ((u16x8*)Xb)[i] = o;
  }
}

// W[K][N] fp32 -> WT[N][K] bf16, LDS-tiled 32x32 (coalesced both sides)
__global__ __launch_bounds__(256) void transpose_cvt(const float* __restrict__ W,
                                                     ushort* __restrict__ WT,
                                                     int K, int N) {
  __shared__ float t[32][33];
  const int tn0 = blockIdx.x * 32, tk0 = blockIdx.y * 32;
  const int tx = threadIdx.x & 31, ty = threadIdx.x >> 5;
#pragma unroll
  for (int i = 0; i < 4; ++i) {
    int k = tk0 + ty + i * 8;
    t[ty + i * 8][tx] = W[(size_t)k * N + tn0 + tx];
  }
  __syncthreads();
#pragma unroll
  for (int i = 0; i < 4; ++i) {
    int n = tn0 + ty + i * 8;
    WT[(size_t)n * K + tk0 + tx] = f2bf(t[tx][ty + i * 8]);
  }
}

// C[M,1536] bf16 = A[M,512] bf16 @ BT[1536,512]^T ; 128x128 tile, BK=32, 4 waves
__global__ __launch_bounds__(256) void gemm_qkv2(const ushort* __restrict__ A,
                                                 const ushort* __restrict__ BT,
                                                 ushort* __restrict__ C) {
  __shared__ __align__(16) ushort as_[128 * 32];
  __shared__ __align__(16) ushort bs_[128 * 32];
  const int tid = threadIdx.x;
  const int lane = tid & 63;
  const int wid = tid >> 6;
  const int c16 = lane & 15, q4 = lane >> 4;
  const int m0 = blockIdx.x * 128, n0 = blockIdx.y * 128;
  const int wr = (wid >> 1) * 64, wc = (wid & 1) * 64;

  f32x4 acc[4][4];
#pragma unroll
  for (int m = 0; m < 4; ++m)
#pragma unroll
    for (int n = 0; n < 4; ++n) acc[m][n] = f32x4{0.f, 0.f, 0.f, 0.f};

  const ushort* aptr = A + (size_t)(m0 + (tid >> 2)) * 512 + (tid & 3) * 8;
  const ushort* bptr = BT + (size_t)(n0 + (tid >> 2)) * 512 + (tid & 3) * 8;
  auto al0 = (__attribute__((address_space(3))) uint*)(as_ + tid * 8);
  auto al1 = (__attribute__((address_space(3))) uint*)(as_ + 2048 + tid * 8);
  auto bl0 = (__attribute__((address_space(3))) uint*)(bs_ + tid * 8);
  auto bl1 = (__attribute__((address_space(3))) uint*)(bs_ + 2048 + tid * 8);
  const ushort* ard = as_ + (wr + c16) * 32 + q4 * 8;
  const ushort* brd = bs_ + (wc + c16) * 32 + q4 * 8;

  for (int k0 = 0; k0 < 512; k0 += 32) {
    if (k0) __syncthreads();
    __builtin_amdgcn_global_load_lds(
        (__attribute__((address_space(1))) uint*)(aptr + k0), al0, 16, 0, 0);
    __builtin_amdgcn_global_load_lds(
        (__attribute__((address_space(1))) uint*)(aptr + 64 * 512 + k0), al1, 16, 0, 0);
    __builtin_amdgcn_global_load_lds(
        (__attribute__((address_space(1))) uint*)(bptr + k0), bl0, 16, 0, 0);
    __builtin_amdgcn_global_load_lds(
        (__attribute__((address_space(1))) uint*)(bptr + 64 * 512 + k0), bl1, 16, 0, 0);
    __syncthreads();
    u16x8 af[4], bf[4];
#pragma unroll
    for (int m = 0; m < 4; ++m) af[m] = *reinterpret_cast<const u16x8*>(ard + m * 512);
#pragma unroll
    for (int n = 0; n < 4; ++n) bf[n] = *reinterpret_cast<const u16x8*>(brd + n * 512);
#pragma unroll
    for (int m = 0; m < 4; ++m)
#pragma unroll
      for (int n = 0; n < 4; ++n) acc[m][n] = mfma_bf16(af[m], bf[n], acc[m][n]);
  }
  const int row0 = m0 + wr + q4 * 4;
  const int col0 = n0 + wc + c16;
#pragma unroll
  for (int m = 0; m < 4; ++m)
#pragma unroll
    for (int r = 0; r < 4; ++r) {
      ushort* cp = C + (size_t)(row0 + m * 16 + r) * 1536 + col0;
      cp[0]  = f2bf(acc[m][0][r]);
      cp[16] = f2bf(acc[m][1][r]);
      cp[32] = f2bf(acc[m][2][r]);
      cp[48] = f2bf(acc[m][3][r]);
    }
}

// per-window attention: one wave per (b, g, head)
__global__ __launch_bounds__(256) void attn_win(const ushort* __restrict__ qkv,
                                                ushort* __restrict__ O) {
  __shared__ __align__(16) ushort p_lds[4][4096];
  __shared__ __align__(16) ushort v_lds[4][4096];
  const int tid = threadIdx.x, lane = tid & 63, w = tid >> 6;
  const int wg = blockIdx.x * 4 + w;
  const int head = wg & 7, g = (wg >> 3) & 63, b = wg >> 9;
  const int gh = g >> 3, gw = g & 7;
  const int c16 = lane & 15, q4 = lane >> 4;
  const size_t brow = (size_t)b * 3136;
  const u16x8 Z = {0, 0, 0, 0, 0, 0, 0, 0};

  int rowq[4]; bool val[4];
#pragma unroll
  for (int i = 0; i < 4; ++i) {
    int s = i * 16 + c16;
    val[i] = (s < 49);
    int ss = val[i] ? s : 0;
    rowq[i] = (gh * 7 + ss / 7) * 56 + gw * 7 + ss % 7;
  }
  const int qc = head * 64 + q4 * 8;

  u16x8 qf[2][4], kf[2][4];
#pragma unroll
  for (int i = 0; i < 4; ++i) {
    const ushort* p = qkv + (brow + rowq[i]) * 1536 + qc;
#pragma unroll
    for (int kk = 0; kk < 2; ++kk) {
      qf[kk][i] = val[i] ? *reinterpret_cast<const u16x8*>(p + kk * 32) : Z;
      kf[kk][i] = val[i] ? *reinterpret_cast<const u16x8*>(p + 512 + kk * 32) : Z;
    }
  }

  // stage V^T (XOR-swizzled): lane covers token t = lane
  {
    int t = lane < 49 ? lane : 0;
    const ushort* vp =
        qkv + (brow + ((gh * 7 + t / 7) * 56 + gw * 7 + t % 7)) * 1536 + 1024 + head * 64;
    u16x8 vr[8];
#pragma unroll
    for (int j = 0; j < 8; ++j)
      vr[j] = (lane < 49) ? *reinterpret_cast<const u16x8*>(vp + j * 8) : Z;
#pragma unroll
    for (int d = 0; d < 64; ++d)
      v_lds[w][(d * 64 + lane) ^ ((d & 7) << 3)] = vr[d >> 3][d & 7];
  }

  f32x4 acc[4][4];
#pragma unroll
  for (int m = 0; m < 4; ++m)
#pragma unroll
    for (int n = 0; n < 4; ++n) acc[m][n] = f32x4{0.f, 0.f, 0.f, 0.f};
#pragma unroll
  for (int kk = 0; kk < 2; ++kk)
#pragma unroll
    for (int m = 0; m < 4; ++m)
#pragma unroll
      for (int n = 0; n < 4; ++n)
        acc[m][n] = mfma_bf16(qf[kk][m], kf[kk][n], acc[m][n]);

  // softmax rows (cols n=0..2 always valid; n=3 valid only for c16==0) + P -> LDS
#pragma unroll
  for (int m = 0; m < 4; ++m)
#pragma unroll
    for (int r = 0; r < 4; ++r) {
      float s0 = acc[m][0][r] * 0.125f;
      float s1 = acc[m][1][r] * 0.125f;
      float s2 = acc[m][2][r] * 0.125f;
      float s3 = (c16 == 0) ? acc[m][3][r] * 0.125f : -1e30f;
      float mx = fmaxf(fmaxf(s0, s1), fmaxf(s2, s3));
#pragma unroll
      for (int off = 1; off < 16; off <<= 1) mx = fmaxf(mx, __shfl_xor(mx, off));
      s0 = __expf(s0 - mx);
      s1 = __expf(s1 - mx);
      s2 = __expf(s2 - mx);
      s3 = (c16 == 0) ? __expf(s3 - mx) : 0.f;
      float sum = s0 + s1 + s2 + s3;
#pragma unroll
      for (int off = 1; off < 16; off <<= 1) sum += __shfl_xor(sum, off);
      float inv = 1.f / sum;
      int row = m * 16 + q4 * 4 + r;
      int rb = row * 64, sw = (row & 7) << 3;
      p_lds[w][(rb + c16) ^ sw]      = f2bf(s0 * inv);
      p_lds[w][(rb + 16 + c16) ^ sw] = f2bf(s1 * inv);
      p_lds[w][(rb + 32 + c16) ^ sw] = f2bf(s2 * inv);
      p_lds[w][(rb + 48 + c16) ^ sw] = f2bf(s3 * inv);
    }
  __syncthreads();

  f32x4 o[4][4];
#pragma unroll
  for (int m = 0; m < 4; ++m)
#pragma unroll
    for (int n = 0; n < 4; ++n) o[m][n] = f32x4{0.f, 0.f, 0.f, 0.f};
#pragma unroll
  for (int kk = 0; kk < 2; ++kk) {
    u16x8 pa[4], vb[4];
#pragma unroll
    for (int m = 0; m < 4; ++m) {
      int row = m * 16 + c16;
      pa[m] = *reinterpret_cast<const u16x8*>(
          &p_lds[w][(row * 64 + kk * 32 + q4 * 8) ^ ((row & 7) << 3)]);
    }
#pragma unroll
    for (int n = 0; n < 4; ++n) {
      int d = n * 16 + c16;
      vb[n] = *reinterpret_cast<const u16x8*>(
          &v_lds[w][(d * 64 + kk * 32 + q4 * 8) ^ ((d & 7) << 3)]);
    }
#pragma unroll
    for (int m = 0; m < 4; ++m)
#pragma unroll
      for (int n = 0; n < 4; ++n) o[m][n] = mfma_bf16(pa[m], vb[n], o[m][n]);
  }

#pragma unroll
  for (int m = 0; m < 4; ++m)
#pragma unroll
    for (int r = 0; r < 4; ++r) {
      int s = m * 16 + q4 * 4 + r;
      if (s < 49) {
        int n_tok = (gh * 7 + s / 7) * 56 + gw * 7 + s % 7;
        ushort* op = O + (brow + n_tok) * 512 + head * 64 + c16;
        op[0]  = f2bf(o[m][0][r]);
        op[16] = f2bf(o[m][1][r]);
        op[32] = f2bf(o[m][2][r]);
        op[48] = f2bf(o[m][3][r]);
      }
    }
}

// C[M,512] fp32 = A[M,512] bf16 @ BT[512,512]^T + bias
__global__ __launch_bounds__(256) void gemm_proj(const ushort* __restrict__ A,
                                                 const ushort* __restrict__ BT,
                                                 const float* __restrict__ bias,
                                                 float* __restrict__ C) {
  __shared__ __align__(16) ushort as_[128 * 32];
  __shared__ __align__(16) ushort bs_[128 * 32];
  const int tid = threadIdx.x;
  const int lane = tid & 63;
  const int wid = tid >> 6;
  const int c16 = lane & 15, q4 = lane >> 4;
  const int m0 = blockIdx.x * 128, n0 = blockIdx.y * 128;
  const int wr = (wid >> 1) * 64, wc = (wid & 1) * 64;

  f32x4 acc[4][4];
#pragma unroll
  for (int m = 0; m < 4; ++m)
#pragma unroll
    for (int n = 0; n < 4; ++n) acc[m][n] = f32x4{0.f, 0.f, 0.f, 0.f};

  const ushort* aptr = A + (size_t)(m0 + (tid >> 2)) * 512 + (tid & 3) * 8;
  const ushort* bptr = BT + (size_t)(n0 + (tid >> 2)) * 512 + (tid & 3) * 8;
  auto al0 = (__attribute__((address_space(3))) uint*)(as_ + tid * 8);
  auto al1 = (__attribute__((address_space(3))) uint*)(as_ + 2048 + tid * 8);
  auto bl0 = (__attribute__((address_space(3))) uint*)(bs_ + tid * 8);
  auto bl1 = (__attribute__((address_space(3))) uint*)(bs_ + 2048 + tid * 8);
  const ushort* ard = as_ + (wr + c16) * 32 + q4 * 8;
  const ushort* brd = bs_ + (wc + c16) * 32 + q4 * 8;

  for (int k0 = 0; k0 < 512; k0 += 32) {
    if (k0) __syncthreads();
    __builtin_amdgcn_global_load_lds(
        (__attribute__((address_space(1))) uint*)(aptr + k0), al0, 16, 0, 0);
    __builtin_amdgcn_global_load_lds(
        (__attribute__((address_space(1))) uint*)(aptr + 64 * 512 + k0), al1, 16, 0, 0);
    __builtin_amdgcn_global_load_lds(
        (__attribute__((address_space(1))) uint*)(bptr + k0), bl0, 16, 0, 0);
    __builtin_amdgcn_global_load_lds(
        (__attribute__((address_space(1))) uint*)(bptr + 64 * 512 + k0), bl1, 16, 0, 0);
    __syncthreads();
    u16x8 af[4], bf[4];
#pragma unroll
    for (int m = 0; m < 4; ++m) af[m] = *reinterpret_cast<const u16x8*>(ard + m * 512);
#pragma unroll
    for (int n = 0; n < 4; ++n) bf[n] = *reinterpret_cast<const u16x8*>(brd + n * 512);
#pragma unroll
    for (int m = 0; m < 4; ++m)
#pragma unroll
      for (int n = 0; n < 4; ++n) acc[m][n] = mfma_bf16(af[m], bf[n], acc[m][n]);
  }
  const int row0 = m0 + wr + q4 * 4;
  const int col0 = n0 + wc + c16;
  const float b0 = bias[col0], b1 = bias[col0 + 16], b2 = bias[col0 + 32], b3 = bias[col0 + 48];
#pragma unroll
  for (int m = 0; m < 4; ++m)
#pragma unroll
    for (int r = 0; r < 4; ++r) {
      float* cp = C + (size_t)(row0 + m * 16 + r) * 512 + col0;
      cp[0]  = acc[m][0][r] + b0;
      cp[16] = acc[m][1][r] + b1;
      cp[32] = acc[m][2][r] + b2;
      cp[48] = acc[m][3][r] + b3;
    }
}

extern "C" void kernel_launch(void* const* d_in, const int* in_sizes, int n_in,
                              void* d_out, int out_size, void* d_ws, size_t ws_size,
                              hipStream_t stream) {
  const float* x      = (const float*)d_in[0];
  const float* w_qkv  = (const float*)d_in[1];
  const float* w_proj = (const float*)d_in[2];
  const float* b_proj = (const float*)d_in[3];
  char* ws = (char*)d_ws;
  ushort* wqkvT  = (ushort*)ws;                       // 1,572,864 B
  ushort* wprojT = (ushort*)(ws + 1572864);           //   524,288 B
  ushort* xb     = (ushort*)(ws + 2097152);           // 102,760,448 B (reused as attn out)
  ushort* qkv    = (ushort*)(ws + 104857600);         // 308,281,344 B
  float* out = (float*)d_out;

  transpose_cvt<<<dim3(48, 16), 256, 0, stream>>>(w_qkv, wqkvT, 512, 1536);
  transpose_cvt<<<dim3(16, 16), 256, 0, stream>>>(w_proj, wprojT, 512, 512);
  cvt_x<<<2048, 256, 0, stream>>>(x, xb, 100352 * 512 / 8);
  gemm_qkv2<<<dim3(784, 12), 256, 0, stream>>>(xb, wqkvT, qkv);
  attn_win<<<4096, 256, 0, stream>>>(qkv, xb);
  gemm_proj<<<dim3(784, 4), 256, 0, stream>>>(xb, wprojT, b_proj, out);
}

// Round 3
// 488.468 us; speedup vs baseline: 1.2436x; 1.0660x over previous
//
#include <hip/hip_runtime.h>

typedef unsigned short ushort;
typedef unsigned int uint;
typedef __bf16 bf16x8 __attribute__((ext_vector_type(8)));
typedef unsigned short u16x8 __attribute__((ext_vector_type(8)));
typedef float f32x4 __attribute__((ext_vector_type(4)));

__device__ __forceinline__ ushort f2bf(float f) {
  uint u = __builtin_bit_cast(uint, f);
  u += 0x7fffu + ((u >> 16) & 1u);
  return (ushort)(u >> 16);
}

__device__ __forceinline__ f32x4 mfma_bf16(u16x8 a, u16x8 b, f32x4 c) {
  return __builtin_amdgcn_mfma_f32_16x16x32_bf16(
      __builtin_bit_cast(bf16x8, a), __builtin_bit_cast(bf16x8, b), c, 0, 0, 0);
}

// x fp32 -> bf16, vectorized 8/thread, grid-stride
__global__ __launch_bounds__(256) void cvt_x(const float* __restrict__ X,
                                             ushort* __restrict__ Xb, int total8) {
  int stride = gridDim.x * 256;
  for (int i = blockIdx.x * 256 + threadIdx.x; i < total8; i += stride) {
    f32x4 a = ((const f32x4*)X)[2 * i];
    f32x4 b = ((const f32x4*)X)[2 * i + 1];
    u16x8 o;
#pragma unroll
    for (int j = 0; j < 4; ++j) { o[j] = f2bf(a[j]); o[j + 4] = f2bf(b[j]); }
    ((u16x8*)Xb)[i] = o;
  }
}

// W[K][N] fp32 -> WT[N][K] bf16, LDS-tiled 32x32
__global__ __launch_bounds__(256) void transpose_cvt(const float* __restrict__ W,
                                                     ushort* __restrict__ WT,
                                                     int K, int N) {
  __shared__ float t[32][33];
  const int tn0 = blockIdx.x * 32, tk0 = blockIdx.y * 32;
  const int tx = threadIdx.x & 31, ty = threadIdx.x >> 5;
#pragma unroll
  for (int i = 0; i < 4; ++i) {
    int k = tk0 + ty + i * 8;
    t[ty + i * 8][tx] = W[(size_t)k * N + tn0 + tx];
  }
  __syncthreads();
#pragma unroll
  for (int i = 0; i < 4; ++i) {
    int n = tn0 + ty + i * 8;
    WT[(size_t)n * K + tk0 + tx] = f2bf(t[tx][ty + i * 8]);
  }
}

// ---------------- 256x256 8-phase counted-vmcnt GEMM, K=512 ----------------
// A[M][512] bf16, BT[N][512] bf16 -> C[M][N]; OUT=0: bf16 store; OUT=1: f32+bias.
// 8 waves (2M x 4N), per-wave 128x64 via interleaved quarters.
// LDS: per K-tile A[256][64]+B[256][64], granule-XOR swizzle (cg ^= row&7),
// applied by pre-swizzling the per-lane GLOBAL source (linear gload_lds dst).

#define GLL(g, l)                                                              \
  __builtin_amdgcn_global_load_lds(                                            \
      (const __attribute__((address_space(1))) uint*)(g),                      \
      (__attribute__((address_space(3))) uint*)(l), 16, 0, 0)
#define BAR() __builtin_amdgcn_s_barrier()
#define SCB() __builtin_amdgcn_sched_barrier(0)
#define WAITV(n) asm volatile("s_waitcnt vmcnt(" #n ")" ::: "memory")

template <int OUT>
__global__ __launch_bounds__(512, 2) void gemm8p(const ushort* __restrict__ A,
                                                 const ushort* __restrict__ BT,
                                                 void* __restrict__ Cout,
                                                 const float* __restrict__ bias,
                                                 const int ldc, const int NT,
                                                 const int CPX) {
  __shared__ __align__(16) ushort as_[2][16384];
  __shared__ __align__(16) ushort bs_[2][16384];
  const int bid = blockIdx.x;
  const int wg = (bid & 7) * CPX + (bid >> 3);  // XCD swizzle (grid % 8 == 0)
  const int mt = wg / NT, nt = wg - mt * NT;    // ntile-inner: A-panel L2 reuse
  const int m0 = mt << 8, n0 = nt << 8;
  const int tid = threadIdx.x, lane = tid & 63, wid = tid >> 6;
  const int wm = wid >> 2, wn = wid & 3;
  const int c16 = lane & 15, q4 = lane >> 4;
  const int sw = c16 & 7;
  const int lrow = lane >> 3, lcg = (lane & 7) ^ lrow;  // stage src swizzle
  const ushort* Ag = A + (size_t)(m0 + wid * 16 + lrow) * 512 + lcg * 8;
  const ushort* Bg = BT + (size_t)(n0 + wid * 16 + lrow) * 512 + lcg * 8;
  const int aro = (wm * 64 + c16) * 64;  // frag-read row base (ushort idx)
  const int bro = (wn * 32 + c16) * 64;
  const int ag0 = (q4 ^ sw) * 8;          // kk=0 granule (swizzled)
  const int ag1 = ((4 + q4) ^ sw) * 8;    // kk=1

  f32x4 acc[8][4];
#pragma unroll
  for (int m = 0; m < 8; ++m)
#pragma unroll
    for (int n = 0; n < 4; ++n) acc[m][n] = f32x4{0.f, 0.f, 0.f, 0.f};
  u16x8 af[4][2], bf0[2][2], bf1[2][2];

#define STAGE_A(half, ktg)                                                     \
  do {                                                                         \
    const ushort* g_ = Ag + (size_t)(half) * (128 * 512) + (ktg) * 64;         \
    ushort* l_ = &as_[(ktg) & 1][(half) * 8192 + wid * 1024 + lane * 8];       \
    GLL(g_, l_);                                                               \
    GLL(g_ + 8 * 512, l_ + 512);                                               \
  } while (0)
#define STAGE_B(half, ktg)                                                     \
  do {                                                                         \
    const ushort* g_ = Bg + (size_t)(half) * (128 * 512) + (ktg) * 64;         \
    ushort* l_ = &bs_[(ktg) & 1][(half) * 8192 + wid * 1024 + lane * 8];       \
    GLL(g_, l_);                                                               \
    GLL(g_ + 8 * 512, l_ + 512);                                               \
  } while (0)
#define LDA(kt, mh)                                                            \
  do {                                                                         \
    const ushort* p_ = &as_[kt][(mh)*8192 + aro];                              \
    _Pragma("unroll") for (int f_ = 0; f_ < 4; ++f_) {                         \
      af[f_][0] = *(const u16x8*)(p_ + f_ * 1024 + ag0);                       \
      af[f_][1] = *(const u16x8*)(p_ + f_ * 1024 + ag1);                       \
    }                                                                          \
  } while (0)
#define LDB(kt, nh, BF)                                                        \
  do {                                                                         \
    const ushort* p_ = &bs_[kt][(nh)*8192 + bro];                              \
    _Pragma("unroll") for (int g_ = 0; g_ < 2; ++g_) {                         \
      BF[g_][0] = *(const u16x8*)(p_ + g_ * 1024 + ag0);                       \
      BF[g_][1] = *(const u16x8*)(p_ + g_ * 1024 + ag1);                       \
    }                                                                          \
  } while (0)
#define MM(mh, nh, BF)                                                         \
  do {                                                                         \
    __builtin_amdgcn_s_setprio(1);                                             \
    _Pragma("unroll") for (int f_ = 0; f_ < 4; ++f_)                           \
        _Pragma("unroll") for (int g_ = 0; g_ < 2; ++g_) {                     \
      f32x4& a_ = acc[(mh)*4 + f_][(nh)*2 + g_];                               \
      a_ = mfma_bf16(af[f_][0], BF[g_][0], a_);                                \
      a_ = mfma_bf16(af[f_][1], BF[g_][1], a_);                                \
    }                                                                          \
    __builtin_amdgcn_s_setprio(0);                                             \
  } while (0)

  // Prologue: steady-state queue positions (i-1)P3..P8
  STAGE_A(0, 0); STAGE_B(1, 0); STAGE_B(0, 0);
  STAGE_A(1, 0); STAGE_A(0, 1); STAGE_B(1, 1);
  WAITV(6); BAR(); SCB();

  for (int i = 0; i < 3; ++i) {
    const int k1g = 2 * i + 1, k2g = 2 * i + 2, k3g = 2 * i + 3;
    // P1: read A(mh0,kt0)+B(nh0,kt0); stage A(mh1,kt1)[this iter]
    LDA(0, 0); LDB(0, 0, bf0); STAGE_A(1, k1g);
    BAR(); MM(0, 0, bf0); WAITV(10); BAR(); SCB();
    // P2: read B(nh1,kt0); stage B(nh0,kt1)[this iter]
    LDB(0, 1, bf1); STAGE_B(0, k1g);
    BAR(); MM(0, 1, bf1); WAITV(8); BAR(); SCB();
    // P3: read A(mh1,kt0); stage A(mh0,kt0')
    LDA(0, 1); STAGE_A(0, k2g);
    BAR(); MM(1, 1, bf1); BAR(); SCB();
    // P4: stage B(nh1,kt0')
    STAGE_B(1, k2g);
    BAR(); MM(1, 0, bf0); WAITV(4); BAR(); SCB();
    // P5: read A(mh0,kt1)+B(nh0,kt1); stage B(nh0,kt0')
    LDA(1, 0); LDB(1, 0, bf0); STAGE_B(0, k2g);
    BAR(); MM(0, 0, bf0); WAITV(10); BAR(); SCB();
    // P6: read B(nh1,kt1); stage A(mh1,kt0')
    LDB(1, 1, bf1); STAGE_A(1, k2g);
    BAR(); MM(0, 1, bf1); WAITV(10); BAR(); SCB();
    // P7: read A(mh1,kt1); stage A(mh0,kt1')
    LDA(1, 1); STAGE_A(0, k3g);
    BAR(); MM(1, 1, bf1); BAR(); SCB();
    // P8: stage B(nh1,kt1')
    STAGE_B(1, k3g);
    BAR(); MM(1, 0, bf0); WAITV(6); BAR(); SCB();
  }
  // Last iteration (kt 6,7): P1/P2 stage own regions; then drain at P4.
  {
    LDA(0, 0); LDB(0, 0, bf0); STAGE_A(1, 7);
    BAR(); MM(0, 0, bf0); WAITV(10); BAR(); SCB();
    LDB(0, 1, bf1); STAGE_B(0, 7);
    BAR(); MM(0, 1, bf1); WAITV(8); BAR(); SCB();
    LDA(0, 1);
    BAR(); MM(1, 1, bf1); BAR(); SCB();
    BAR(); MM(1, 0, bf0); WAITV(0); BAR(); SCB();
    LDA(1, 0); LDB(1, 0, bf0);
    BAR(); MM(0, 0, bf0); BAR(); SCB();
    LDB(1, 1, bf1);
    BAR(); MM(0, 1, bf1); BAR(); SCB();
    LDA(1, 1);
    BAR(); MM(1, 1, bf1); BAR(); SCB();
    BAR(); MM(1, 0, bf0);
  }

  // Epilogue: row = m0 + mh*128 + wm*64 + f*16 + q4*4 + r
  //           col = n0 + nh*128 + wn*32 + g*16 + c16
  const int crow = m0 + wm * 64 + q4 * 4;
  const int ccol = n0 + wn * 32 + c16;
  if constexpr (OUT == 0) {
    ushort* C = (ushort*)Cout;
#pragma unroll
    for (int mf = 0; mf < 8; ++mf) {
      const int ro = (mf >> 2) * 128 + (mf & 3) * 16;
#pragma unroll
      for (int r = 0; r < 4; ++r) {
        ushort* cp = C + (size_t)(crow + ro + r) * ldc + ccol;
        cp[0]   = f2bf(acc[mf][0][r]);
        cp[16]  = f2bf(acc[mf][1][r]);
        cp[128] = f2bf(acc[mf][2][r]);
        cp[144] = f2bf(acc[mf][3][r]);
      }
    }
  } else {
    float* C = (float*)Cout;
    const float b0 = bias[ccol], b1 = bias[ccol + 16];
    const float b2 = bias[ccol + 128], b3 = bias[ccol + 144];
#pragma unroll
    for (int mf = 0; mf < 8; ++mf) {
      const int ro = (mf >> 2) * 128 + (mf & 3) * 16;
#pragma unroll
      for (int r = 0; r < 4; ++r) {
        float* cp = C + (size_t)(crow + ro + r) * ldc + ccol;
        cp[0]   = acc[mf][0][r] + b0;
        cp[16]  = acc[mf][1][r] + b1;
        cp[128] = acc[mf][2][r] + b2;
        cp[144] = acc[mf][3][r] + b3;
      }
    }
  }
#undef STAGE_A
#undef STAGE_B
#undef LDA
#undef LDB
#undef MM
}

// per-window attention: one wave per (b, g, head)
__global__ __launch_bounds__(256) void attn_win(const ushort* __restrict__ qkv,
                                                ushort* __restrict__ O) {
  __shared__ __align__(16) ushort p_lds[4][4096];
  __shared__ __align__(16) ushort v_lds[4][4096];
  const int tid = threadIdx.x, lane = tid & 63, w = tid >> 6;
  const int wg = blockIdx.x * 4 + w;
  const int head = wg & 7, g = (wg >> 3) & 63, b = wg >> 9;
  const int gh = g >> 3, gw = g & 7;
  const int c16 = lane & 15, q4 = lane >> 4;
  const size_t brow = (size_t)b * 3136;
  const u16x8 Z = {0, 0, 0, 0, 0, 0, 0, 0};

  int rowq[4]; bool val[4];
#pragma unroll
  for (int i = 0; i < 4; ++i) {
    int s = i * 16 + c16;
    val[i] = (s < 49);
    int ss = val[i] ? s : 0;
    rowq[i] = (gh * 7 + ss / 7) * 56 + gw * 7 + ss % 7;
  }
  const int qc = head * 64 + q4 * 8;

  u16x8 qf[2][4], kf[2][4];
#pragma unroll
  for (int i = 0; i < 4; ++i) {
    const ushort* p = qkv + (brow + rowq[i]) * 1536 + qc;
#pragma unroll
    for (int kk = 0; kk < 2; ++kk) {
      qf[kk][i] = val[i] ? *reinterpret_cast<const u16x8*>(p + kk * 32) : Z;
      kf[kk][i] = val[i] ? *reinterpret_cast<const u16x8*>(p + 512 + kk * 32) : Z;
    }
  }

  {
    int t = lane < 49 ? lane : 0;
    const ushort* vp =
        qkv + (brow + ((gh * 7 + t / 7) * 56 + gw * 7 + t % 7)) * 1536 + 1024 + head * 64;
    u16x8 vr[8];
#pragma unroll
    for (int j = 0; j < 8; ++j)
      vr[j] = (lane < 49) ? *reinterpret_cast<const u16x8*>(vp + j * 8) : Z;
#pragma unroll
    for (int d = 0; d < 64; ++d)
      v_lds[w][(d * 64 + lane) ^ ((d & 7) << 3)] = vr[d >> 3][d & 7];
  }

  f32x4 acc[4][4];
#pragma unroll
  for (int m = 0; m < 4; ++m)
#pragma unroll
    for (int n = 0; n < 4; ++n) acc[m][n] = f32x4{0.f, 0.f, 0.f, 0.f};
#pragma unroll
  for (int kk = 0; kk < 2; ++kk)
#pragma unroll
    for (int m = 0; m < 4; ++m)
#pragma unroll
      for (int n = 0; n < 4; ++n)
        acc[m][n] = mfma_bf16(qf[kk][m], kf[kk][n], acc[m][n]);

#pragma unroll
  for (int m = 0; m < 4; ++m)
#pragma unroll
    for (int r = 0; r < 4; ++r) {
      float s0 = acc[m][0][r] * 0.125f;
      float s1 = acc[m][1][r] * 0.125f;
      float s2 = acc[m][2][r] * 0.125f;
      float s3 = (c16 == 0) ? acc[m][3][r] * 0.125f : -1e30f;
      float mx = fmaxf(fmaxf(s0, s1), fmaxf(s2, s3));
#pragma unroll
      for (int off = 1; off < 16; off <<= 1) mx = fmaxf(mx, __shfl_xor(mx, off));
      s0 = __expf(s0 - mx);
      s1 = __expf(s1 - mx);
      s2 = __expf(s2 - mx);
      s3 = (c16 == 0) ? __expf(s3 - mx) : 0.f;
      float sum = s0 + s1 + s2 + s3;
#pragma unroll
      for (int off = 1; off < 16; off <<= 1) sum += __shfl_xor(sum, off);
      float inv = 1.f / sum;
      int row = m * 16 + q4 * 4 + r;
      int rb = row * 64, sw = (row & 7) << 3;
      p_lds[w][(rb + c16) ^ sw]      = f2bf(s0 * inv);
      p_lds[w][(rb + 16 + c16) ^ sw] = f2bf(s1 * inv);
      p_lds[w][(rb + 32 + c16) ^ sw] = f2bf(s2 * inv);
      p_lds[w][(rb + 48 + c16) ^ sw] = f2bf(s3 * inv);
    }
  __syncthreads();

  f32x4 o[4][4];
#pragma unroll
  for (int m = 0; m < 4; ++m)
#pragma unroll
    for (int n = 0; n < 4; ++n) o[m][n] = f32x4{0.f, 0.f, 0.f, 0.f};
#pragma unroll
  for (int kk = 0; kk < 2; ++kk) {
    u16x8 pa[4], vb[4];
#pragma unroll
    for (int m = 0; m < 4; ++m) {
      int row = m * 16 + c16;
      pa[m] = *reinterpret_cast<const u16x8*>(
          &p_lds[w][(row * 64 + kk * 32 + q4 * 8) ^ ((row & 7) << 3)]);
    }
#pragma unroll
    for (int n = 0; n < 4; ++n) {
      int d = n * 16 + c16;
      vb[n] = *reinterpret_cast<const u16x8*>(
          &v_lds[w][(d * 64 + kk * 32 + q4 * 8) ^ ((d & 7) << 3)]);
    }
#pragma unroll
    for (int m = 0; m < 4; ++m)
#pragma unroll
      for (int n = 0; n < 4; ++n) o[m][n] = mfma_bf16(pa[m], vb[n], o[m][n]);
  }

#pragma unroll
  for (int m = 0; m < 4; ++m)
#pragma unroll
    for (int r = 0; r < 4; ++r) {
      int s = m * 16 + q4 * 4 + r;
      if (s < 49) {
        int n_tok = (gh * 7 + s / 7) * 56 + gw * 7 + s % 7;
        ushort* op = O + (brow + n_tok) * 512 + head * 64 + c16;
        op[0]  = f2bf(o[m][0][r]);
        op[16] = f2bf(o[m][1][r]);
        op[32] = f2bf(o[m][2][r]);
        op[48] = f2bf(o[m][3][r]);
      }
    }
}

extern "C" void kernel_launch(void* const* d_in, const int* in_sizes, int n_in,
                              void* d_out, int out_size, void* d_ws, size_t ws_size,
                              hipStream_t stream) {
  const float* x      = (const float*)d_in[0];
  const float* w_qkv  = (const float*)d_in[1];
  const float* w_proj = (const float*)d_in[2];
  const float* b_proj = (const float*)d_in[3];
  char* ws = (char*)d_ws;
  ushort* wqkvT  = (ushort*)ws;                       // 1,572,864 B
  ushort* wprojT = (ushort*)(ws + 1572864);           //   524,288 B
  ushort* xb     = (ushort*)(ws + 2097152);           // 102,760,448 B (reused as attn out)
  ushort* qkv    = (ushort*)(ws + 104857600);         // 308,281,344 B
  float* out = (float*)d_out;

  transpose_cvt<<<dim3(48, 16), 256, 0, stream>>>(w_qkv, wqkvT, 512, 1536);
  transpose_cvt<<<dim3(16, 16), 256, 0, stream>>>(w_proj, wprojT, 512, 512);
  cvt_x<<<2048, 256, 0, stream>>>(x, xb, 100352 * 512 / 8);
  // M=100352 -> 392 mtiles; GEMM1: 6 ntiles -> 2352 blocks (2352/8=294/XCD)
  gemm8p<0><<<2352, 512, 0, stream>>>(xb, wqkvT, (void*)qkv, nullptr, 1536, 6, 294);
  attn_win<<<4096, 256, 0, stream>>>(qkv, xb);
  // GEMM2: 2 ntiles -> 784 blocks (98/XCD)
  gemm8p<1><<<784, 512, 0, stream>>>(xb, wprojT, (void*)out, b_proj, 512, 2, 98);
}